// Round 1
// baseline (459.778 us; speedup 1.0000x reference)
//
#include <hip/hip_runtime.h>

// Problem constants (from reference)
#define DCOLS 32        // dist/angle columns
#define WCOLS 32        // idx_t/index_t columns
#define NUM_CLASSES 22
#define ONEHOT_COLS (NUM_CLASSES * WCOLS)   // 704
#define OUT_COLS (ONEHOT_COLS + WCOLS + WCOLS)  // 768

// ---------------------------------------------------------------------------
// Kernel 1: seed min/max accumulators in workspace.
// All candidate values are >= 0 (uniform [0,1) plus sentinel zeros), so
// int-ordered atomicMin/atomicMax on the raw float bits preserve float order.
__global__ void init_minmax(int* __restrict__ ws) {
    ws[0] = 0x7f800000;  // +inf  (atomicMin target)
    ws[1] = 0;           // 0.0f  (atomicMax target; max >= 0 always)
}

// ---------------------------------------------------------------------------
// Kernel 2: global min/max over the gathered dist_t[h,w] values.
__global__ __launch_bounds__(256) void minmax_kernel(
    const float* __restrict__ dist,
    const int*   __restrict__ index_t,
    const int*   __restrict__ index_h,
    int*         __restrict__ ws,
    int total)  // total = H * WCOLS
{
    float vmin = __int_as_float(0x7f800000);
    float vmax = 0.0f;
    for (int i = blockIdx.x * blockDim.x + threadIdx.x; i < total;
         i += gridDim.x * blockDim.x) {
        const int h  = i >> 5;          // WCOLS == 32
        const int it = index_t[i];
        float v = 0.0f;
        if (it < DCOLS) v = dist[index_h[h] * DCOLS + it];
        vmin = fminf(vmin, v);
        vmax = fmaxf(vmax, v);
    }
    // wave-64 butterfly-ish shuffle reduce
    #pragma unroll
    for (int off = 32; off > 0; off >>= 1) {
        vmin = fminf(vmin, __shfl_down(vmin, off, 64));
        vmax = fmaxf(vmax, __shfl_down(vmax, off, 64));
    }
    __shared__ float smin[4], smax[4];
    const int lane = threadIdx.x & 63;
    const int wave = threadIdx.x >> 6;
    if (lane == 0) { smin[wave] = vmin; smax[wave] = vmax; }
    __syncthreads();
    if (threadIdx.x == 0) {
        float m = smin[0], M = smax[0];
        #pragma unroll
        for (int k = 1; k < 4; ++k) { m = fminf(m, smin[k]); M = fmaxf(M, smax[k]); }
        atomicMin(ws,     __float_as_int(m));   // valid: all values >= 0
        atomicMax(ws + 1, __float_as_int(M));
    }
}

// ---------------------------------------------------------------------------
// Kernel 3: one block per output row; 192 threads x float4 = 768 cols.
// Region boundaries (704, 736) are multiples of 4 -> every float4 store is
// region-pure and fully coalesced (global_store_dwordx4).
__global__ __launch_bounds__(192) void fill_kernel(
    const float* __restrict__ dist,
    const float* __restrict__ angle,
    const int*   __restrict__ idx_t,
    const int*   __restrict__ index_t,
    const int*   __restrict__ index_h,
    const int*   __restrict__ ws,
    float*       __restrict__ out)
{
    const int h   = blockIdx.x;
    const int tid = threadIdx.x;

    __shared__ int   s_idx[WCOLS];
    __shared__ float s_dist[WCOLS];
    __shared__ float s_angle[WCOLS];

    if (tid < WCOLS) {
        const float dmin = __int_as_float(ws[0]);
        const float dmax = __int_as_float(ws[1]);
        const float inv  = 1.0f / (dmax - dmin);
        s_idx[tid] = idx_t[h * WCOLS + tid];
        const int it = index_t[h * WCOLS + tid];
        float dv = 0.0f, av = 0.0f;
        if (it < DCOLS) {
            const int base = index_h[h] * DCOLS;
            dv = dist[base + it];
            av = angle[base + it];
        }
        s_dist[tid]  = (dv - dmin) * inv;
        s_angle[tid] = av;
    }
    __syncthreads();

    const int j0 = tid * 4;
    float vals[4];
    #pragma unroll
    for (int k = 0; k < 4; ++k) {
        const int j = j0 + k;
        float v;
        if (j < ONEHOT_COLS) {
            const int w = j / NUM_CLASSES;       // magic-mul div by const
            const int c = j - w * NUM_CLASSES;
            v = (s_idx[w] == c) ? 1.0f : 0.0f;
        } else if (j < ONEHOT_COLS + WCOLS) {
            v = s_dist[j - ONEHOT_COLS];
        } else {
            v = s_angle[j - (ONEHOT_COLS + WCOLS)];
        }
        vals[k] = v;
    }
    float4* o = reinterpret_cast<float4*>(out + (size_t)h * OUT_COLS);
    o[tid] = make_float4(vals[0], vals[1], vals[2], vals[3]);
}

// ---------------------------------------------------------------------------
extern "C" void kernel_launch(void* const* d_in, const int* in_sizes, int n_in,
                              void* d_out, int out_size, void* d_ws, size_t ws_size,
                              hipStream_t stream) {
    const float* dist    = (const float*)d_in[0];
    const float* angle   = (const float*)d_in[1];
    const int*   idx_t   = (const int*)d_in[2];
    const int*   index_t = (const int*)d_in[3];
    const int*   index_h = (const int*)d_in[4];
    float*       out     = (float*)d_out;
    int*         ws      = (int*)d_ws;

    const int H     = in_sizes[4];      // index_h has H elements
    const int total = H * WCOLS;

    hipLaunchKernelGGL(init_minmax, dim3(1), dim3(1), 0, stream, ws);
    hipLaunchKernelGGL(minmax_kernel, dim3(2048), dim3(256), 0, stream,
                       dist, index_t, index_h, ws, total);
    hipLaunchKernelGGL(fill_kernel, dim3(H), dim3(192), 0, stream,
                       dist, angle, idx_t, index_t, index_h, ws, out);
}

// Round 2
// 408.189 us; speedup vs baseline: 1.1264x; 1.1264x over previous
//
#include <hip/hip_runtime.h>

// Problem constants (from reference)
#define DCOLS 32        // dist/angle columns
#define WCOLS 32        // idx_t/index_t columns
#define NUM_CLASSES 22
#define ONEHOT_COLS (NUM_CLASSES * WCOLS)       // 704
#define OUT_COLS (ONEHOT_COLS + WCOLS + WCOLS)  // 768
#define ROWS_PER_BLOCK 4

// ---------------------------------------------------------------------------
// Min/max encoding (seeded by an 8-byte hipMemsetAsync of 0xFF):
//   ws[0] (uint): running MIN of bits(-v).  v>=0 -> -v is a negative float;
//     for negative floats, smaller uint bits == larger float == smaller v.
//     So uint-min of bits(-v) tracks min(v).  Seed 0xFFFFFFFF >= everything.
//   ws[1] (int):  running MAX of bits(v).   v>=0 -> bits are positive ints,
//     int order == float order.  Seed 0xFFFFFFFF == -1 <= everything.
// Recover: dmin = -as_float(ws[0]);  dmax = as_float(ws[1]).

// ---------------------------------------------------------------------------
// Kernel 1: global min/max over the gathered dist_t[h,w] values.
// int4-vectorized: 4 consecutive elements share the same h (32 % 4 == 0).
__global__ __launch_bounds__(256) void minmax_kernel(
    const float* __restrict__ dist,
    const int*   __restrict__ index_t,
    const int*   __restrict__ index_h,
    unsigned*    __restrict__ ws,
    int total4)  // total4 = H * WCOLS / 4
{
    float vmin = __int_as_float(0x7f800000);  // +inf
    float vmax = 0.0f;
    const int stride = gridDim.x * blockDim.x;
    for (int i4 = blockIdx.x * blockDim.x + threadIdx.x; i4 < total4; i4 += stride) {
        const int4 it = reinterpret_cast<const int4*>(index_t)[i4];
        const int  h  = i4 >> 3;              // (i4*4) >> 5
        const int  row = index_h[h] * DCOLS;
        float v0 = 0.0f, v1 = 0.0f, v2 = 0.0f, v3 = 0.0f;
        if (it.x < DCOLS) v0 = dist[row + it.x];
        if (it.y < DCOLS) v1 = dist[row + it.y];
        if (it.z < DCOLS) v2 = dist[row + it.z];
        if (it.w < DCOLS) v3 = dist[row + it.w];
        vmin = fminf(fminf(fminf(vmin, v0), fminf(v1, v2)), v3);
        vmax = fmaxf(fmaxf(fmaxf(vmax, v0), fmaxf(v1, v2)), v3);
    }
    // wave-64 shuffle reduce
    #pragma unroll
    for (int off = 32; off > 0; off >>= 1) {
        vmin = fminf(vmin, __shfl_down(vmin, off, 64));
        vmax = fmaxf(vmax, __shfl_down(vmax, off, 64));
    }
    __shared__ float smin[4], smax[4];
    const int lane = threadIdx.x & 63;
    const int wave = threadIdx.x >> 6;
    if (lane == 0) { smin[wave] = vmin; smax[wave] = vmax; }
    __syncthreads();
    if (threadIdx.x == 0) {
        float m = smin[0], M = smax[0];
        #pragma unroll
        for (int k = 1; k < 4; ++k) { m = fminf(m, smin[k]); M = fmaxf(M, smax[k]); }
        atomicMin(ws,              __float_as_uint(-m));
        atomicMax((int*)(ws + 1),  __float_as_int(M));
    }
}

// ---------------------------------------------------------------------------
// Kernel 2: 4 rows per 256-thread block. Each thread stores 3 float4s at
// out + h0*768 + t*4 for t = tid, tid+256, tid+512 -> the block's 12 KB of
// stores are perfectly contiguous (global_store_dwordx4, fully coalesced).
__global__ __launch_bounds__(256) void fill_kernel(
    const float* __restrict__ dist,
    const float* __restrict__ angle,
    const int*   __restrict__ idx_t,
    const int*   __restrict__ index_t,
    const int*   __restrict__ index_h,
    const unsigned* __restrict__ ws,
    float*       __restrict__ out,
    int H)
{
    const int h0  = blockIdx.x * ROWS_PER_BLOCK;
    const int tid = threadIdx.x;

    __shared__ int   s_idx[ROWS_PER_BLOCK][WCOLS];
    __shared__ float s_dist[ROWS_PER_BLOCK][WCOLS];
    __shared__ float s_angle[ROWS_PER_BLOCK][WCOLS];

    if (tid < ROWS_PER_BLOCK * WCOLS) {       // 128 loader threads
        const float dmin = -__uint_as_float(ws[0]);
        const float dmax =  __uint_as_float(ws[1]);
        const float inv  = 1.0f / (dmax - dmin);
        const int r = tid >> 5;
        const int c = tid & 31;
        const int h = h0 + r;
        if (h < H) {
            const int it = index_t[h * WCOLS + c];
            s_idx[r][c] = idx_t[h * WCOLS + c];
            float dv = 0.0f, av = 0.0f;
            if (it < DCOLS) {
                const int base = index_h[h] * DCOLS;
                dv = dist[base + it];
                av = angle[base + it];
            }
            s_dist[r][c]  = (dv - dmin) * inv;
            s_angle[r][c] = av;
        }
    }
    __syncthreads();

    const bool full = (h0 + ROWS_PER_BLOCK) <= H;
    #pragma unroll
    for (int m = 0; m < 3; ++m) {
        const int t    = m * 256 + tid;       // 0..767 across the block
        const int row  = t / 192;             // const-div -> mul/shift
        const int col4 = t - row * 192;
        const int j0   = col4 * 4;
        float vals[4];
        #pragma unroll
        for (int k = 0; k < 4; ++k) {
            const int j = j0 + k;
            float v;
            if (j < ONEHOT_COLS) {
                const int w = j / NUM_CLASSES;
                const int c = j - w * NUM_CLASSES;
                v = (s_idx[row][w] == c) ? 1.0f : 0.0f;
            } else if (j < ONEHOT_COLS + WCOLS) {
                v = s_dist[row][j - ONEHOT_COLS];
            } else {
                v = s_angle[row][j - (ONEHOT_COLS + WCOLS)];
            }
            vals[k] = v;
        }
        if (full) {
            float4* o = reinterpret_cast<float4*>(out + (size_t)h0 * OUT_COLS);
            o[t] = make_float4(vals[0], vals[1], vals[2], vals[3]);
        } else if (h0 + row < H) {
            float4* o = reinterpret_cast<float4*>(out + (size_t)(h0 + row) * OUT_COLS);
            o[col4] = make_float4(vals[0], vals[1], vals[2], vals[3]);
        }
    }
}

// ---------------------------------------------------------------------------
extern "C" void kernel_launch(void* const* d_in, const int* in_sizes, int n_in,
                              void* d_out, int out_size, void* d_ws, size_t ws_size,
                              hipStream_t stream) {
    const float* dist    = (const float*)d_in[0];
    const float* angle   = (const float*)d_in[1];
    const int*   idx_t   = (const int*)d_in[2];
    const int*   index_t = (const int*)d_in[3];
    const int*   index_h = (const int*)d_in[4];
    float*       out     = (float*)d_out;
    unsigned*    ws      = (unsigned*)d_ws;

    const int H      = in_sizes[4];           // index_h has H elements
    const int total4 = (H * WCOLS) / 4;       // H*32 always divisible by 4

    // Seed both min/max accumulators with 0xFFFFFFFF (see encoding above).
    hipMemsetAsync(ws, 0xFF, 8, stream);

    hipLaunchKernelGGL(minmax_kernel, dim3(1024), dim3(256), 0, stream,
                       dist, index_t, index_h, ws, total4);

    const int fill_blocks = (H + ROWS_PER_BLOCK - 1) / ROWS_PER_BLOCK;
    hipLaunchKernelGGL(fill_kernel, dim3(fill_blocks), dim3(256), 0, stream,
                       dist, angle, idx_t, index_t, index_h, ws, out, H);
}

// Round 4
// 373.493 us; speedup vs baseline: 1.2310x; 1.0929x over previous
//
#include <hip/hip_runtime.h>

// Problem constants (from reference)
#define DCOLS 32        // dist/angle columns
#define WCOLS 32        // idx_t/index_t columns
#define NUM_CLASSES 22
#define ONEHOT_COLS (NUM_CLASSES * WCOLS)       // 704
#define OUT_COLS (ONEHOT_COLS + WCOLS + WCOLS)  // 768
#define ROWS_PER_BLOCK 8                        // 8 rows x 32 cols = 256 gather threads

// native clang vector type — __builtin_nontemporal_store requires it
typedef float vfloat4 __attribute__((ext_vector_type(4)));

// ---------------------------------------------------------------------------
// Min/max encoding (seeded by an 8-byte hipMemsetAsync of 0xFF):
//   ws[0] (uint): running MIN of bits(-v).  v>=0 -> -v is a negative float;
//     for negative floats, smaller uint bits == larger float == smaller v.
//     So uint-min of bits(-v) tracks min(v).  Seed 0xFFFFFFFF >= everything.
//   ws[1] (int):  running MAX of bits(v).   v>=0 -> bits order == float order.
//     Seed 0xFFFFFFFF == -1 <= everything.
// Recover: dmin = -as_float(ws[0]);  dmax = as_float(ws[1]).

// ---------------------------------------------------------------------------
// Kernel 1: global min/max over the gathered dist_t[h,w] values.
// int4-vectorized: 4 consecutive elements share the same h (32 % 4 == 0).
__global__ __launch_bounds__(256) void minmax_kernel(
    const float* __restrict__ dist,
    const int*   __restrict__ index_t,
    const int*   __restrict__ index_h,
    unsigned*    __restrict__ ws,
    int total4)  // total4 = H * WCOLS / 4
{
    float vmin = __int_as_float(0x7f800000);  // +inf
    float vmax = 0.0f;
    const int stride = gridDim.x * blockDim.x;
    for (int i4 = blockIdx.x * blockDim.x + threadIdx.x; i4 < total4; i4 += stride) {
        const int4 it = reinterpret_cast<const int4*>(index_t)[i4];
        const int  h  = i4 >> 3;              // (i4*4) >> 5
        const int  row = index_h[h] * DCOLS;  // index_h cacheline-broadcast
        float v0 = 0.0f, v1 = 0.0f, v2 = 0.0f, v3 = 0.0f;
        if (it.x < DCOLS) v0 = dist[row + it.x];
        if (it.y < DCOLS) v1 = dist[row + it.y];
        if (it.z < DCOLS) v2 = dist[row + it.z];
        if (it.w < DCOLS) v3 = dist[row + it.w];
        vmin = fminf(fminf(fminf(vmin, v0), fminf(v1, v2)), v3);
        vmax = fmaxf(fmaxf(fmaxf(vmax, v0), fmaxf(v1, v2)), v3);
    }
    // wave-64 shuffle reduce
    #pragma unroll
    for (int off = 32; off > 0; off >>= 1) {
        vmin = fminf(vmin, __shfl_down(vmin, off, 64));
        vmax = fmaxf(vmax, __shfl_down(vmax, off, 64));
    }
    __shared__ float smin[4], smax[4];
    const int lane = threadIdx.x & 63;
    const int wave = threadIdx.x >> 6;
    if (lane == 0) { smin[wave] = vmin; smax[wave] = vmax; }
    __syncthreads();
    if (threadIdx.x == 0) {
        float m = smin[0], M = smax[0];
        #pragma unroll
        for (int k = 1; k < 4; ++k) { m = fminf(m, smin[k]); M = fmaxf(M, smax[k]); }
        atomicMin(ws,             __float_as_uint(-m));
        atomicMax((int*)(ws + 1), __float_as_int(M));
    }
}

// ---------------------------------------------------------------------------
// Kernel 2: 8 rows per 256-thread block.
//  - All 256 threads perform one gather each (8 rows x 32 cols) -> 2x the
//    in-flight scattered loads per block vs the 128-loader version.
//  - Each thread stores 6 float4s; the block's 1536 float4s (24 KB) are
//    perfectly contiguous starting at out + h0*768.
//  - Output is write-once: nontemporal stores keep the 25.6 MB dist/angle
//    gather working set resident in the per-XCD L2 instead of being evicted
//    by 307 MB of streaming writes.
__global__ __launch_bounds__(256) void fill_kernel(
    const float* __restrict__ dist,
    const float* __restrict__ angle,
    const int*   __restrict__ idx_t,
    const int*   __restrict__ index_t,
    const int*   __restrict__ index_h,
    const unsigned* __restrict__ ws,
    float*       __restrict__ out,
    int H)
{
    const int h0  = blockIdx.x * ROWS_PER_BLOCK;
    const int tid = threadIdx.x;

    __shared__ int   s_idx[ROWS_PER_BLOCK][WCOLS];
    __shared__ float s_dist[ROWS_PER_BLOCK][WCOLS];
    __shared__ float s_angle[ROWS_PER_BLOCK][WCOLS];

    {
        const float dmin = -__uint_as_float(ws[0]);
        const float dmax =  __uint_as_float(ws[1]);
        const float inv  = 1.0f / (dmax - dmin);
        const int r = tid >> 5;
        const int c = tid & 31;
        const int h = h0 + r;
        if (h < H) {
            const int it = index_t[h * WCOLS + c];
            s_idx[r][c] = idx_t[h * WCOLS + c];
            float dv = 0.0f, av = 0.0f;
            if (it < DCOLS) {
                const int base = index_h[h] * DCOLS;
                dv = dist[base + it];
                av = angle[base + it];
            }
            s_dist[r][c]  = (dv - dmin) * inv;
            s_angle[r][c] = av;
        }
    }
    __syncthreads();

    const bool full = (h0 + ROWS_PER_BLOCK) <= H;
    #pragma unroll
    for (int m = 0; m < 6; ++m) {
        const int t    = m * 256 + tid;       // 0..1535 across the block
        const int row  = t / 192;             // const-div -> mul/shift
        const int col4 = t - row * 192;
        const int j0   = col4 * 4;
        vfloat4 v4;
        #pragma unroll
        for (int k = 0; k < 4; ++k) {
            const int j = j0 + k;
            float v;
            if (j < ONEHOT_COLS) {
                const int w = j / NUM_CLASSES;
                const int c = j - w * NUM_CLASSES;
                v = (s_idx[row][w] == c) ? 1.0f : 0.0f;
            } else if (j < ONEHOT_COLS + WCOLS) {
                v = s_dist[row][j - ONEHOT_COLS];
            } else {
                v = s_angle[row][j - (ONEHOT_COLS + WCOLS)];
            }
            v4[k] = v;
        }
        if (full) {
            vfloat4* o = reinterpret_cast<vfloat4*>(out + (size_t)h0 * OUT_COLS);
            __builtin_nontemporal_store(v4, o + t);
        } else if (h0 + row < H) {
            vfloat4* o = reinterpret_cast<vfloat4*>(out + (size_t)(h0 + row) * OUT_COLS);
            __builtin_nontemporal_store(v4, o + col4);
        }
    }
}

// ---------------------------------------------------------------------------
extern "C" void kernel_launch(void* const* d_in, const int* in_sizes, int n_in,
                              void* d_out, int out_size, void* d_ws, size_t ws_size,
                              hipStream_t stream) {
    const float* dist    = (const float*)d_in[0];
    const float* angle   = (const float*)d_in[1];
    const int*   idx_t   = (const int*)d_in[2];
    const int*   index_t = (const int*)d_in[3];
    const int*   index_h = (const int*)d_in[4];
    float*       out     = (float*)d_out;
    unsigned*    ws      = (unsigned*)d_ws;

    const int H      = in_sizes[4];           // index_h has H elements
    const int total4 = (H * WCOLS) / 4;       // H*32 always divisible by 4

    // Seed both min/max accumulators with 0xFFFFFFFF (see encoding above).
    (void)hipMemsetAsync(ws, 0xFF, 8, stream);

    hipLaunchKernelGGL(minmax_kernel, dim3(1024), dim3(256), 0, stream,
                       dist, index_t, index_h, ws, total4);

    const int fill_blocks = (H + ROWS_PER_BLOCK - 1) / ROWS_PER_BLOCK;
    hipLaunchKernelGGL(fill_kernel, dim3(fill_blocks), dim3(256), 0, stream,
                       dist, angle, idx_t, index_t, index_h, ws, out, H);
}